// Round 8
// baseline (1519.045 us; speedup 1.0000x reference)
//
#include <hip/hip_runtime.h>

#define NN   729
#define NF   730   // N+1
#define BV   8
#define KK   32
#define NBAS 40
#define MAXIT 10
#define PI_F 3.14159265358979323846f

#define MTH   1024  // mix threads (16 waves = 4 waves/EU, one block/CU)
#define BT    16    // steps per block
#define AST   448   // padded max active rows; CactT stride
#define NSLOT 60    // bulk row slots (960 lanes / 16 lanes-per-row)
#define NPASS 8     // 60*8 = 480 >= 448

typedef float v2f __attribute__((ext_vector_type(2)));

__device__ __forceinline__ v2f fma2(float c, v2f d, v2f w) {
    w.x = fmaf(c, d.x, w.x);
    w.y = fmaf(c, d.y, w.y);
    return w;
}

// ---------------- build Ct (730x730), Ct[i][j] = C[j][i] ----------------
__global__ void build_C_kernel(const float* __restrict__ coeff,
                               const float* __restrict__ upper,
                               const float* __restrict__ basis,
                               float* __restrict__ Ct) {
    int idx = blockIdx.x * blockDim.x + threadIdx.x;
    if (idx >= NF * NF) return;
    int i = idx / NF, j = idx - i * NF;   // (i,j) of C; coalesced basis reads
    float val;
    if (i == 0) {
        val = (j == 0) ? 0.f : upper[j - 1];
    } else if (j == 0) {
        val = upper[i - 1];
    } else {
        float acc = 0.f;
        const float* bp = basis + (size_t)(i - 1) * NN + (j - 1);
        #pragma unroll 8
        for (int b = 0; b < NBAS; ++b)
            acc = fmaf(coeff[b], bp[(size_t)b * NN * NN], acc);
        val = acc;
    }
    Ct[(size_t)j * NF + i] = val;
}

// ---------------- init V  (B x 730 x 32) ----------------
__global__ void init_V_kernel(const float* __restrict__ z,
                              const float* __restrict__ vraw,
                              float* __restrict__ V) {
    int g = threadIdx.x >> 5;
    int k = threadIdx.x & 31;
    int row = blockIdx.x * 8 + g;           // 0..5839
    int b = row / NF, n = row - b * NF;
    const float* vr = vraw + (size_t)b * NF * KK;

    float v0 = vr[k];
    float s2 = v0 * v0;
    #pragma unroll
    for (int off = 16; off; off >>= 1) s2 += __shfl_xor(s2, off, 32);
    v0 = v0 / sqrtf(s2);

    float vn = vr[(size_t)n * KK + k];
    float d = vn * v0;
    #pragma unroll
    for (int off = 16; off; off >>= 1) d += __shfl_xor(d, off, 32);
    float u = vn - d * v0;
    float un2 = u * u;
    #pragma unroll
    for (int off = 16; off; off >>= 1) un2 += __shfl_xor(un2, off, 32);
    u = u / fmaxf(sqrtf(un2), 1e-8f);

    float zf = (n == 0) ? 1.f : z[b * NN + (n - 1)];
    float c = cosf(PI_F * zf), s = sinf(PI_F * zf);
    float outv = -c * v0 + s * u;
    if (n == 0) outv = v0;
    V[((size_t)b * NF + n) * KK + k] = outv;
}

// ---------------- build per-batch active lists (perm order) ----------------
__global__ void build_act_kernel(const int* __restrict__ is_input,
                                 const int* __restrict__ perm,
                                 int* __restrict__ act, int* __restrict__ nA_arr) {
    int b = blockIdx.x, l = threadIdx.x;   // 64 threads = 1 wave
    int base = 0;
    for (int c = 0; c < (NN + 63) / 64; ++c) {
        int idx = c * 64 + l;
        bool f = false; int pi = 0;
        if (idx < NN) { pi = perm[idx]; f = (is_input[b * NN + pi - 1] == 0); }
        unsigned long long m = __ballot(f);
        int pos = __popcll(m & ((1ull << l) - 1ull));
        if (f && base + pos < AST) act[b * AST + base + pos] = pi;
        base += __popcll(m);
    }
    if (base > AST) base = AST;
    if (l == 0) nA_arr[b] = base;
    for (int p = base + l; p < AST; p += 64) act[b * AST + p] = 0;
}

// --- gather CactT[b][a][t] = C[r_t][r_a] = Ct[r_a][r_t] (row-coalesced) ---
__global__ void gather_CactT_kernel(const float* __restrict__ Ct,
                                    const int* __restrict__ act,
                                    float* __restrict__ CactT) {
    int a = blockIdx.x, b = blockIdx.y;
    __shared__ int acts[AST];
    for (int i = threadIdx.x; i < AST; i += blockDim.x) acts[i] = act[b * AST + i];
    __syncthreads();
    const float* src = Ct + (size_t)acts[a] * NF;
    float* dst = CactT + ((size_t)b * AST + a) * AST;
    for (int t = threadIdx.x; t < AST; t += blockDim.x)
        dst[t] = src[acts[t]];
}

// ------- init W (compact): W[a] = sum_j Ct[ra][j] V[j] - Cd V[ra] -------
__global__ void init_W_kernel(const float* __restrict__ Ct,
                              const int* __restrict__ act,
                              const int* __restrict__ nA_arr,
                              const float* __restrict__ V,
                              float* __restrict__ Wc) {
    int b = blockIdx.y;
    int a = blockIdx.x * 8 + (threadIdx.x >> 5);
    int k = threadIdx.x & 31;
    int nA = nA_arr[b];
    float w = 0.f;
    if (a < nA) {
        int ra = act[b * AST + a];
        const float* ctr = Ct + (size_t)ra * NF;
        const float* vb = V + (size_t)b * NF * KK + k;
        float acc = 0.f;
        for (int j = 0; j < NF; ++j)
            acc = fmaf(ctr[j], vb[(size_t)j * KK], acc);
        float cd = ctr[ra];
        w = acc - cd * V[((size_t)b * NF + ra) * KK + k];
    }
    Wc[((size_t)b * AST + a) * KK + k] = w;
}

// 16-lane row sum via DPP row rotations (pure VALU)
__device__ __forceinline__ float rowsum16(float x) {
    int y;
    y = __builtin_amdgcn_update_dpp(0, __float_as_int(x), 0x121, 0xF, 0xF, false);
    x += __int_as_float(y);
    y = __builtin_amdgcn_update_dpp(0, __float_as_int(x), 0x122, 0xF, 0xF, false);
    x += __int_as_float(y);
    y = __builtin_amdgcn_update_dpp(0, __float_as_int(x), 0x124, 0xF, 0xF, false);
    x += __int_as_float(y);
    y = __builtin_amdgcn_update_dpp(0, __float_as_int(x), 0x128, 0xF, 0xF, false);
    x += __int_as_float(y);
    return x;
}

// ---------------- mixing: W in registers, 2-barrier 16-step blocks --------
// waves_per_eu(4,4) pins the allocator to 4 waves/EU -> 128-VGPR budget.
// (R6/R7: default heuristic targeted 8 waves/EU -> 64 VGPR -> ~50 regs
// spilled -> WRITE_SIZE 1 MB of scratch traffic per dispatch.)
__global__ __launch_bounds__(MTH) __attribute__((amdgpu_waves_per_eu(4, 4)))
void mix_kernel(const float* __restrict__ CactT_g,
                const float* __restrict__ Wc,
                const int* __restrict__ act_g,
                const int* __restrict__ nA_arr,
                const int* __restrict__ is_input,
                const float* __restrict__ z,
                const float* __restrict__ Vg,
                float* __restrict__ out) {
    __shared__ float V_c[AST * KK];        // 57344 B
    __shared__ float gpub[BT * KK];        // 2048 B
    __shared__ float dv_s[2][BT * KK];     // 4096 B
    __shared__ float cblk_s[2][BT * BT];   // 2048 B
    __shared__ float cmini_s[2][BT * BT];  // 2048 B
    __shared__ float Cd_s[AST];            // 1792 B
    __shared__ int   act_s[AST];           // 1792 B
    __shared__ int   slot_s[NF];           // 2920 B

    int b = blockIdx.x, tid = threadIdx.x;
    const float* CactT_b = CactT_g + (size_t)b * AST * AST;
    int nA = nA_arr[b];
    int nblkp = (nA + BT - 1) / BT;
    if (nblkp < 2) nblkp = 2;
    int nAp = nblkp * BT;
    int totB = MAXIT * nblkp;

    int wid = tid >> 6;
    bool isbulk = (tid >= 64);
    int lane = isbulk ? (tid - 64) : 0;
    int kp = lane & 15;           // k-pair index: floats 2kp, 2kp+1
    int slot = lane >> 4;         // 0..59

    // ---- setup ----
    if (tid < AST) act_s[tid] = act_g[b * AST + tid];
    __syncthreads();
    for (int idx = tid; idx < nAp * KK; idx += MTH)
        V_c[idx] = Vg[((size_t)b * NF + act_s[idx >> 5]) * KK + (idx & 31)];
    if (tid < nA) slot_s[act_s[tid]] = tid;
    if (tid < AST) Cd_s[tid] = CactT_b[(size_t)tid * AST + tid];
    if (tid < 256) {   // cblk for block 0: cblk[t*16+u] = CactT[u][t]
        int t = tid >> 4, u = tid & 15;
        cblk_s[0][t * BT + u] = CactT_b[(size_t)u * AST + t];
    }
    // W rows into registers: lane owns rows a = slot + 60p, element pair kp
    v2f w[NPASS];
    #pragma unroll
    for (int p = 0; p < NPASS; ++p) {
        int a = slot + NSLOT * p;
        v2f zz = {0.f, 0.f};
        w[p] = zz;
        if (isbulk && a < AST)
            w[p] = *(const v2f*)&Wc[((size_t)b * AST + a) * KK + 2 * kp];
    }
    __syncthreads();

    for (int bi = 0; bi < totB; ++bi) {
        int blk = bi % nblkp, s0 = blk * BT;
        int pblk = (bi - 1 + nblkp) % nblkp, sp0 = pblk * BT;  // junk at bi=0
        int cb = bi & 1, pv = cb ^ 1;
        int sn0 = ((bi + 1) % nblkp) * BT;

        // ---- phase 1: owners of current block apply prev dv + publish ----
        if (isbulk) {
            #pragma unroll
            for (int p = 0; p < NPASS; ++p) {
                int a = slot + NSLOT * p;
                if ((a >> 4) == blk) {
                    int u = a - s0;
                    if (bi > 0) {
                        #pragma unroll
                        for (int t = 0; t < BT; ++t) {
                            float c = cmini_s[cb][u * BT + t];
                            v2f d = *(const v2f*)&dv_s[pv][t * KK + 2 * kp];
                            w[p] = fma2(c, d, w[p]);
                        }
                    }
                    *(v2f*)&gpub[u * KK + 2 * kp] = w[p];
                }
            }
        }
        __syncthreads();

        // ---- phase 2: serial (wave 0) || bulk sweep (waves 1-15) ----
        if (wid == 0) {
            int ll = tid & 15;
            float g0[BT], g1[BT];
            #pragma unroll
            for (int u = 0; u < BT; ++u) {
                g0[u] = gpub[u * KK + ll];
                g1[u] = gpub[u * KK + ll + 16];
            }
            #pragma unroll
            for (int u = 0; u < BT; ++u) {
                int s = s0 + u;
                float n2 = fmaf(g0[u], g0[u], g1[u] * g1[u]);
                n2 = rowsum16(n2);
                float inv = -__builtin_amdgcn_rsqf(fmaxf(n2, 1e-16f));
                float vo0 = V_c[s * KK + ll];
                float vo1 = V_c[s * KK + ll + 16];
                float msk = (s < nA) ? 1.f : 0.f;
                float d0 = fmaf(g0[u], inv, -vo0) * msk;
                float d1 = fmaf(g1[u], inv, -vo1) * msk;
                if (tid < 16) {
                    dv_s[cb][u * KK + ll]      = d0;
                    dv_s[cb][u * KK + ll + 16] = d1;
                    V_c[s * KK + ll]      = vo0 + d0;
                    V_c[s * KK + ll + 16] = vo1 + d1;
                }
                #pragma unroll
                for (int u2 = u + 1; u2 < BT; ++u2) {
                    float c = cblk_s[cb][u * BT + u2];
                    g0[u2] = fmaf(c, d0, g0[u2]);
                    g1[u2] = fmaf(c, d1, g1[u2]);
                }
            }
        } else {
            // stagers for next iteration's tiles
            if (wid == 14) {   // cmini: rows of next block x cols of this block
                int l = tid & 63; int u = l & 15, q = l >> 4;
                float4 v = *(const float4*)&CactT_b[(size_t)(sn0 + u) * AST + s0 + 4 * q];
                *(float4*)&cmini_s[pv][u * BT + 4 * q] = v;
            }
            if (wid == 15) {   // cblk: next block's intra tile (transposed store)
                int l = tid & 63; int u = l & 15, q = l >> 4;
                float4 v = *(const float4*)&CactT_b[(size_t)(sn0 + u) * AST + sn0 + 4 * q];
                cblk_s[pv][(4 * q + 0) * BT + u] = v.x;
                cblk_s[pv][(4 * q + 1) * BT + u] = v.y;
                cblk_s[pv][(4 * q + 2) * BT + u] = v.z;
                cblk_s[pv][(4 * q + 3) * BT + u] = v.w;
            }
            // bulk: apply prev dv to all owned rows except current block
            if (bi > 0) {
                v2f dvv[BT];
                #pragma unroll
                for (int t = 0; t < BT; ++t)
                    dvv[t] = *(const v2f*)&dv_s[pv][t * KK + 2 * kp];
                const float* cbase = CactT_b + sp0;
                float4 c0[4], c1[4];
                {
                    const float* r0 = cbase + (size_t)slot * AST;
                    c0[0] = *(const float4*)(r0);
                    c0[1] = *(const float4*)(r0 + 4);
                    c0[2] = *(const float4*)(r0 + 8);
                    c0[3] = *(const float4*)(r0 + 12);
                }
                #pragma unroll
                for (int p = 0; p < NPASS; ++p) {
                    // prefetch pass p+1 into the other buffer (ping-pong)
                    if (p < NPASS - 1) {
                        int an = slot + NSLOT * (p + 1);
                        const float* rn = cbase + (size_t)((an < AST) ? an : slot) * AST;
                        if (p & 1) {
                            c0[0] = *(const float4*)(rn);
                            c0[1] = *(const float4*)(rn + 4);
                            c0[2] = *(const float4*)(rn + 8);
                            c0[3] = *(const float4*)(rn + 12);
                        } else {
                            c1[0] = *(const float4*)(rn);
                            c1[1] = *(const float4*)(rn + 4);
                            c1[2] = *(const float4*)(rn + 8);
                            c1[3] = *(const float4*)(rn + 12);
                        }
                    }
                    float4 q0 = (p & 1) ? c1[0] : c0[0];
                    float4 q1 = (p & 1) ? c1[1] : c0[1];
                    float4 q2 = (p & 1) ? c1[2] : c0[2];
                    float4 q3 = (p & 1) ? c1[3] : c0[3];
                    int a = slot + NSLOT * p;
                    if (a < nAp && (a >> 4) != blk) {
                        w[p] = fma2(q0.x, dvv[0],  w[p]);
                        w[p] = fma2(q0.y, dvv[1],  w[p]);
                        w[p] = fma2(q0.z, dvv[2],  w[p]);
                        w[p] = fma2(q0.w, dvv[3],  w[p]);
                        w[p] = fma2(q1.x, dvv[4],  w[p]);
                        w[p] = fma2(q1.y, dvv[5],  w[p]);
                        w[p] = fma2(q1.z, dvv[6],  w[p]);
                        w[p] = fma2(q1.w, dvv[7],  w[p]);
                        w[p] = fma2(q2.x, dvv[8],  w[p]);
                        w[p] = fma2(q2.y, dvv[9],  w[p]);
                        w[p] = fma2(q2.z, dvv[10], w[p]);
                        w[p] = fma2(q2.w, dvv[11], w[p]);
                        w[p] = fma2(q3.x, dvv[12], w[p]);
                        w[p] = fma2(q3.y, dvv[13], w[p]);
                        w[p] = fma2(q3.z, dvv[14], w[p]);
                        w[p] = fma2(q3.w, dvv[15], w[p]);
                        if ((a >> 4) == pblk) {   // cancel self (diag) term
                            v2f dd = *(const v2f*)&dv_s[pv][(a - sp0) * KK + 2 * kp];
                            w[p] = fma2(-Cd_s[a], dd, w[p]);
                        }
                    }
                }
            }
        }
        __syncthreads();
    }

    // ---- epilogue: z_out ----
    int k = tid & 31, r = tid >> 5;
    float v0k = Vg[(size_t)b * NF * KK + k];
    for (int n = 1 + r; n <= NN; n += 32) {
        int ii = is_input[b * NN + n - 1];
        float res;
        if (ii == 1) {
            res = z[b * NN + n - 1];
        } else {
            int a = slot_s[n];
            float dot = V_c[a * KK + k] * v0k;
            #pragma unroll
            for (int off = 16; off; off >>= 1) dot += __shfl_xor(dot, off, 32);
            float ca = fminf(fmaxf(-dot, -1.f + 1e-6f), 1.f - 1e-6f);
            res = acosf(ca) * (1.f / PI_F);
        }
        if (k == 0) out[b * NN + n - 1] = res;
    }
}

extern "C" void kernel_launch(void* const* d_in, const int* in_sizes, int n_in,
                              void* d_out, int out_size, void* d_ws, size_t ws_size,
                              hipStream_t stream) {
    const float* coeff    = (const float*)d_in[0];
    const float* upper    = (const float*)d_in[1];
    const float* basis    = (const float*)d_in[2];
    const float* z        = (const float*)d_in[3];
    const int*   is_input = (const int*)d_in[4];
    const float* vraw     = (const float*)d_in[5];
    const int*   perm     = (const int*)d_in[6];
    float* out = (float*)d_out;

    float* ws    = (float*)d_ws;
    float* Ct    = ws;                              // 730*730
    float* V     = Ct + (size_t)NF * NF;            // 8*730*32
    float* CactT = V + (size_t)BV * NF * KK;        // 8*448*448
    float* Wc    = CactT + (size_t)BV * AST * AST;  // 8*448*32
    int*   act   = (int*)(Wc + (size_t)BV * AST * KK);  // 8*448
    int*   nAa   = act + BV * AST;                  // 8
    // total ws ≈ 9.8 MB

    build_C_kernel<<<dim3((NF * NF + 255) / 256), dim3(256), 0, stream>>>(coeff, upper, basis, Ct);
    init_V_kernel<<<dim3(730), dim3(256), 0, stream>>>(z, vraw, V);
    build_act_kernel<<<dim3(BV), dim3(64), 0, stream>>>(is_input, perm, act, nAa);
    gather_CactT_kernel<<<dim3(AST, BV), dim3(256), 0, stream>>>(Ct, act, CactT);
    init_W_kernel<<<dim3(AST / 8, BV), dim3(256), 0, stream>>>(Ct, act, nAa, V, Wc);
    mix_kernel<<<dim3(BV), dim3(MTH), 0, stream>>>(CactT, Wc, act, nAa, is_input, z, V, out);
}

// Round 9
// 1508.101 us; speedup vs baseline: 1.0073x; 1.0073x over previous
//
#include <hip/hip_runtime.h>

#define NN   729
#define NF   730   // N+1
#define BV   8
#define KK   32
#define NBAS 40
#define MAXIT 10
#define PI_F 3.14159265358979323846f

#define MTH   1024  // mix threads (16 waves = 4 waves/EU, one block/CU)
#define BT    16    // steps per block
#define AST   448   // padded max active rows; CactT stride
#define NSLOT 60    // bulk row slots (960 lanes / 16 lanes-per-row)
#define NPASS 8     // 60*8 = 480 >= 448
// LDS pad: push total LDS past 163840/2 so only ONE block fits per CU.
// The compiler's VGPR budget = 512 / (max waves/EU by occupancy); at
// 2 blocks/CU it targets 8 waves/EU -> 64 VGPR -> massive spills
// (R6-R8: WRITE_SIZE 1 MB of scratch). 1 block/CU -> 4 waves/EU -> 128.
#define VPAD  2176

typedef float v2f __attribute__((ext_vector_type(2)));

__device__ __forceinline__ v2f fma2(float c, v2f d, v2f w) {
    w.x = fmaf(c, d.x, w.x);
    w.y = fmaf(c, d.y, w.y);
    return w;
}

// ---------------- build Ct (730x730), Ct[i][j] = C[j][i] ----------------
__global__ void build_C_kernel(const float* __restrict__ coeff,
                               const float* __restrict__ upper,
                               const float* __restrict__ basis,
                               float* __restrict__ Ct) {
    int idx = blockIdx.x * blockDim.x + threadIdx.x;
    if (idx >= NF * NF) return;
    int i = idx / NF, j = idx - i * NF;   // (i,j) of C; coalesced basis reads
    float val;
    if (i == 0) {
        val = (j == 0) ? 0.f : upper[j - 1];
    } else if (j == 0) {
        val = upper[i - 1];
    } else {
        float acc = 0.f;
        const float* bp = basis + (size_t)(i - 1) * NN + (j - 1);
        #pragma unroll 8
        for (int b = 0; b < NBAS; ++b)
            acc = fmaf(coeff[b], bp[(size_t)b * NN * NN], acc);
        val = acc;
    }
    Ct[(size_t)j * NF + i] = val;
}

// ---------------- init V  (B x 730 x 32) ----------------
__global__ void init_V_kernel(const float* __restrict__ z,
                              const float* __restrict__ vraw,
                              float* __restrict__ V) {
    int g = threadIdx.x >> 5;
    int k = threadIdx.x & 31;
    int row = blockIdx.x * 8 + g;           // 0..5839
    int b = row / NF, n = row - b * NF;
    const float* vr = vraw + (size_t)b * NF * KK;

    float v0 = vr[k];
    float s2 = v0 * v0;
    #pragma unroll
    for (int off = 16; off; off >>= 1) s2 += __shfl_xor(s2, off, 32);
    v0 = v0 / sqrtf(s2);

    float vn = vr[(size_t)n * KK + k];
    float d = vn * v0;
    #pragma unroll
    for (int off = 16; off; off >>= 1) d += __shfl_xor(d, off, 32);
    float u = vn - d * v0;
    float un2 = u * u;
    #pragma unroll
    for (int off = 16; off; off >>= 1) un2 += __shfl_xor(un2, off, 32);
    u = u / fmaxf(sqrtf(un2), 1e-8f);

    float zf = (n == 0) ? 1.f : z[b * NN + (n - 1)];
    float c = cosf(PI_F * zf), s = sinf(PI_F * zf);
    float outv = -c * v0 + s * u;
    if (n == 0) outv = v0;
    V[((size_t)b * NF + n) * KK + k] = outv;
}

// ---------------- build per-batch active lists (perm order) ----------------
__global__ void build_act_kernel(const int* __restrict__ is_input,
                                 const int* __restrict__ perm,
                                 int* __restrict__ act, int* __restrict__ nA_arr) {
    int b = blockIdx.x, l = threadIdx.x;   // 64 threads = 1 wave
    int base = 0;
    for (int c = 0; c < (NN + 63) / 64; ++c) {
        int idx = c * 64 + l;
        bool f = false; int pi = 0;
        if (idx < NN) { pi = perm[idx]; f = (is_input[b * NN + pi - 1] == 0); }
        unsigned long long m = __ballot(f);
        int pos = __popcll(m & ((1ull << l) - 1ull));
        if (f && base + pos < AST) act[b * AST + base + pos] = pi;
        base += __popcll(m);
    }
    if (base > AST) base = AST;
    if (l == 0) nA_arr[b] = base;
    for (int p = base + l; p < AST; p += 64) act[b * AST + p] = 0;
}

// --- gather CactT[b][a][t] = C[r_t][r_a] = Ct[r_a][r_t] (row-coalesced) ---
__global__ void gather_CactT_kernel(const float* __restrict__ Ct,
                                    const int* __restrict__ act,
                                    float* __restrict__ CactT) {
    int a = blockIdx.x, b = blockIdx.y;
    __shared__ int acts[AST];
    for (int i = threadIdx.x; i < AST; i += blockDim.x) acts[i] = act[b * AST + i];
    __syncthreads();
    const float* src = Ct + (size_t)acts[a] * NF;
    float* dst = CactT + ((size_t)b * AST + a) * AST;
    for (int t = threadIdx.x; t < AST; t += blockDim.x)
        dst[t] = src[acts[t]];
}

// ------- init W (compact): W[a] = sum_j Ct[ra][j] V[j] - Cd V[ra] -------
__global__ void init_W_kernel(const float* __restrict__ Ct,
                              const int* __restrict__ act,
                              const int* __restrict__ nA_arr,
                              const float* __restrict__ V,
                              float* __restrict__ Wc) {
    int b = blockIdx.y;
    int a = blockIdx.x * 8 + (threadIdx.x >> 5);
    int k = threadIdx.x & 31;
    int nA = nA_arr[b];
    float w = 0.f;
    if (a < nA) {
        int ra = act[b * AST + a];
        const float* ctr = Ct + (size_t)ra * NF;
        const float* vb = V + (size_t)b * NF * KK + k;
        float acc = 0.f;
        for (int j = 0; j < NF; ++j)
            acc = fmaf(ctr[j], vb[(size_t)j * KK], acc);
        float cd = ctr[ra];
        w = acc - cd * V[((size_t)b * NF + ra) * KK + k];
    }
    Wc[((size_t)b * AST + a) * KK + k] = w;
}

// 16-lane row sum via DPP row rotations (pure VALU)
__device__ __forceinline__ float rowsum16(float x) {
    int y;
    y = __builtin_amdgcn_update_dpp(0, __float_as_int(x), 0x121, 0xF, 0xF, false);
    x += __int_as_float(y);
    y = __builtin_amdgcn_update_dpp(0, __float_as_int(x), 0x122, 0xF, 0xF, false);
    x += __int_as_float(y);
    y = __builtin_amdgcn_update_dpp(0, __float_as_int(x), 0x124, 0xF, 0xF, false);
    x += __int_as_float(y);
    y = __builtin_amdgcn_update_dpp(0, __float_as_int(x), 0x128, 0xF, 0xF, false);
    x += __int_as_float(y);
    return x;
}

// ---------------- mixing: W in registers, 2-barrier 16-step blocks --------
__global__ __launch_bounds__(MTH) __attribute__((amdgpu_waves_per_eu(4, 4)))
void mix_kernel(const float* __restrict__ CactT_g,
                const float* __restrict__ Wc,
                const int* __restrict__ act_g,
                const int* __restrict__ nA_arr,
                const int* __restrict__ is_input,
                const float* __restrict__ z,
                const float* __restrict__ Vg,
                float* __restrict__ out) {
    __shared__ float V_c[AST * KK + VPAD]; // 66048 B (VPAD pushes LDS > 80 KB)
    __shared__ float gpub[BT * KK];        // 2048 B
    __shared__ float dv_s[2][BT * KK];     // 4096 B
    __shared__ float cblk_s[2][BT * BT];   // 2048 B
    __shared__ float cmini_s[2][BT * BT];  // 2048 B
    __shared__ float Cd_s[AST];            // 1792 B
    __shared__ int   act_s[AST];           // 1792 B
    __shared__ int   slot_s[NF];           // 2920 B

    int b = blockIdx.x, tid = threadIdx.x;
    const float* CactT_b = CactT_g + (size_t)b * AST * AST;
    int nA = nA_arr[b];
    int nblkp = (nA + BT - 1) / BT;
    if (nblkp < 2) nblkp = 2;
    int nAp = nblkp * BT;
    int totB = MAXIT * nblkp;

    int wid = tid >> 6;
    bool isbulk = (tid >= 64);
    int lane = isbulk ? (tid - 64) : 0;
    int kp = lane & 15;           // k-pair index: floats 2kp, 2kp+1
    int slot = lane >> 4;         // 0..59

    // ---- setup ----
    if (tid < AST) act_s[tid] = act_g[b * AST + tid];
    __syncthreads();
    for (int idx = tid; idx < nAp * KK; idx += MTH)
        V_c[idx] = Vg[((size_t)b * NF + act_s[idx >> 5]) * KK + (idx & 31)];
    if (tid < nA) slot_s[act_s[tid]] = tid;
    if (tid < AST) Cd_s[tid] = CactT_b[(size_t)tid * AST + tid];
    if (tid < 256) {   // cblk for block 0: cblk[t*16+u] = CactT[u][t]
        int t = tid >> 4, u = tid & 15;
        cblk_s[0][t * BT + u] = CactT_b[(size_t)u * AST + t];
    }
    // keep the pad region live so LDS allocation isn't shrunk
    if (tid == 0) V_c[AST * KK + VPAD - 1] = 0.f;
    // W rows into registers: lane owns rows a = slot + 60p, element pair kp
    v2f w[NPASS];
    #pragma unroll
    for (int p = 0; p < NPASS; ++p) {
        int a = slot + NSLOT * p;
        v2f zz = {0.f, 0.f};
        w[p] = zz;
        if (isbulk && a < AST)
            w[p] = *(const v2f*)&Wc[((size_t)b * AST + a) * KK + 2 * kp];
    }
    __syncthreads();

    for (int bi = 0; bi < totB; ++bi) {
        int blk = bi % nblkp, s0 = blk * BT;
        int pblk = (bi - 1 + nblkp) % nblkp, sp0 = pblk * BT;  // junk at bi=0
        int cb = bi & 1, pv = cb ^ 1;
        int sn0 = ((bi + 1) % nblkp) * BT;

        // ---- phase 1: owners of current block apply prev dv + publish ----
        if (isbulk) {
            #pragma unroll
            for (int p = 0; p < NPASS; ++p) {
                int a = slot + NSLOT * p;
                if ((a >> 4) == blk) {
                    int u = a - s0;
                    if (bi > 0) {
                        #pragma unroll
                        for (int t = 0; t < BT; ++t) {
                            float c = cmini_s[cb][u * BT + t];
                            v2f d = *(const v2f*)&dv_s[pv][t * KK + 2 * kp];
                            w[p] = fma2(c, d, w[p]);
                        }
                    }
                    *(v2f*)&gpub[u * KK + 2 * kp] = w[p];
                }
            }
        }
        __syncthreads();

        // ---- phase 2: serial (wave 0) || bulk sweep (waves 1-15) ----
        if (wid == 0) {
            int ll = tid & 15;
            float g0[BT], g1[BT];
            #pragma unroll
            for (int u = 0; u < BT; ++u) {
                g0[u] = gpub[u * KK + ll];
                g1[u] = gpub[u * KK + ll + 16];
            }
            #pragma unroll
            for (int u = 0; u < BT; ++u) {
                int s = s0 + u;
                float n2 = fmaf(g0[u], g0[u], g1[u] * g1[u]);
                n2 = rowsum16(n2);
                float inv = -__builtin_amdgcn_rsqf(fmaxf(n2, 1e-16f));
                float vo0 = V_c[s * KK + ll];
                float vo1 = V_c[s * KK + ll + 16];
                float msk = (s < nA) ? 1.f : 0.f;
                float d0 = fmaf(g0[u], inv, -vo0) * msk;
                float d1 = fmaf(g1[u], inv, -vo1) * msk;
                if (tid < 16) {
                    dv_s[cb][u * KK + ll]      = d0;
                    dv_s[cb][u * KK + ll + 16] = d1;
                    V_c[s * KK + ll]      = vo0 + d0;
                    V_c[s * KK + ll + 16] = vo1 + d1;
                }
                #pragma unroll
                for (int u2 = u + 1; u2 < BT; ++u2) {
                    float c = cblk_s[cb][u * BT + u2];
                    g0[u2] = fmaf(c, d0, g0[u2]);
                    g1[u2] = fmaf(c, d1, g1[u2]);
                }
            }
        } else {
            // stagers for next iteration's tiles
            if (wid == 14) {   // cmini: rows of next block x cols of this block
                int l = tid & 63; int u = l & 15, q = l >> 4;
                float4 v = *(const float4*)&CactT_b[(size_t)(sn0 + u) * AST + s0 + 4 * q];
                *(float4*)&cmini_s[pv][u * BT + 4 * q] = v;
            }
            if (wid == 15) {   // cblk: next block's intra tile (transposed store)
                int l = tid & 63; int u = l & 15, q = l >> 4;
                float4 v = *(const float4*)&CactT_b[(size_t)(sn0 + u) * AST + sn0 + 4 * q];
                cblk_s[pv][(4 * q + 0) * BT + u] = v.x;
                cblk_s[pv][(4 * q + 1) * BT + u] = v.y;
                cblk_s[pv][(4 * q + 2) * BT + u] = v.z;
                cblk_s[pv][(4 * q + 3) * BT + u] = v.w;
            }
            // bulk: apply prev dv to all owned rows except current block
            if (bi > 0) {
                v2f dvv[BT];
                #pragma unroll
                for (int t = 0; t < BT; ++t)
                    dvv[t] = *(const v2f*)&dv_s[pv][t * KK + 2 * kp];
                const float* cbase = CactT_b + sp0;
                float4 c0[4], c1[4];
                {
                    const float* r0 = cbase + (size_t)slot * AST;
                    c0[0] = *(const float4*)(r0);
                    c0[1] = *(const float4*)(r0 + 4);
                    c0[2] = *(const float4*)(r0 + 8);
                    c0[3] = *(const float4*)(r0 + 12);
                }
                #pragma unroll
                for (int p = 0; p < NPASS; ++p) {
                    // prefetch pass p+1 into the other buffer (ping-pong)
                    if (p < NPASS - 1) {
                        int an = slot + NSLOT * (p + 1);
                        const float* rn = cbase + (size_t)((an < AST) ? an : slot) * AST;
                        if (p & 1) {
                            c0[0] = *(const float4*)(rn);
                            c0[1] = *(const float4*)(rn + 4);
                            c0[2] = *(const float4*)(rn + 8);
                            c0[3] = *(const float4*)(rn + 12);
                        } else {
                            c1[0] = *(const float4*)(rn);
                            c1[1] = *(const float4*)(rn + 4);
                            c1[2] = *(const float4*)(rn + 8);
                            c1[3] = *(const float4*)(rn + 12);
                        }
                    }
                    float4 q0 = (p & 1) ? c1[0] : c0[0];
                    float4 q1 = (p & 1) ? c1[1] : c0[1];
                    float4 q2 = (p & 1) ? c1[2] : c0[2];
                    float4 q3 = (p & 1) ? c1[3] : c0[3];
                    int a = slot + NSLOT * p;
                    if (a < nAp && (a >> 4) != blk) {
                        w[p] = fma2(q0.x, dvv[0],  w[p]);
                        w[p] = fma2(q0.y, dvv[1],  w[p]);
                        w[p] = fma2(q0.z, dvv[2],  w[p]);
                        w[p] = fma2(q0.w, dvv[3],  w[p]);
                        w[p] = fma2(q1.x, dvv[4],  w[p]);
                        w[p] = fma2(q1.y, dvv[5],  w[p]);
                        w[p] = fma2(q1.z, dvv[6],  w[p]);
                        w[p] = fma2(q1.w, dvv[7],  w[p]);
                        w[p] = fma2(q2.x, dvv[8],  w[p]);
                        w[p] = fma2(q2.y, dvv[9],  w[p]);
                        w[p] = fma2(q2.z, dvv[10], w[p]);
                        w[p] = fma2(q2.w, dvv[11], w[p]);
                        w[p] = fma2(q3.x, dvv[12], w[p]);
                        w[p] = fma2(q3.y, dvv[13], w[p]);
                        w[p] = fma2(q3.z, dvv[14], w[p]);
                        w[p] = fma2(q3.w, dvv[15], w[p]);
                        if ((a >> 4) == pblk) {   // cancel self (diag) term
                            v2f dd = *(const v2f*)&dv_s[pv][(a - sp0) * KK + 2 * kp];
                            w[p] = fma2(-Cd_s[a], dd, w[p]);
                        }
                    }
                }
            }
        }
        __syncthreads();
    }

    // ---- epilogue: z_out ----
    int k = tid & 31, r = tid >> 5;
    float v0k = Vg[(size_t)b * NF * KK + k];
    for (int n = 1 + r; n <= NN; n += 32) {
        int ii = is_input[b * NN + n - 1];
        float res;
        if (ii == 1) {
            res = z[b * NN + n - 1];
        } else {
            int a = slot_s[n];
            float dot = V_c[a * KK + k] * v0k;
            #pragma unroll
            for (int off = 16; off; off >>= 1) dot += __shfl_xor(dot, off, 32);
            float ca = fminf(fmaxf(-dot, -1.f + 1e-6f), 1.f - 1e-6f);
            res = acosf(ca) * (1.f / PI_F);
        }
        if (k == 0) out[b * NN + n - 1] = res;
    }
}

extern "C" void kernel_launch(void* const* d_in, const int* in_sizes, int n_in,
                              void* d_out, int out_size, void* d_ws, size_t ws_size,
                              hipStream_t stream) {
    const float* coeff    = (const float*)d_in[0];
    const float* upper    = (const float*)d_in[1];
    const float* basis    = (const float*)d_in[2];
    const float* z        = (const float*)d_in[3];
    const int*   is_input = (const int*)d_in[4];
    const float* vraw     = (const float*)d_in[5];
    const int*   perm     = (const int*)d_in[6];
    float* out = (float*)d_out;

    float* ws    = (float*)d_ws;
    float* Ct    = ws;                              // 730*730
    float* V     = Ct + (size_t)NF * NF;            // 8*730*32
    float* CactT = V + (size_t)BV * NF * KK;        // 8*448*448
    float* Wc    = CactT + (size_t)BV * AST * AST;  // 8*448*32
    int*   act   = (int*)(Wc + (size_t)BV * AST * KK);  // 8*448
    int*   nAa   = act + BV * AST;                  // 8
    // total ws ≈ 9.8 MB

    build_C_kernel<<<dim3((NF * NF + 255) / 256), dim3(256), 0, stream>>>(coeff, upper, basis, Ct);
    init_V_kernel<<<dim3(730), dim3(256), 0, stream>>>(z, vraw, V);
    build_act_kernel<<<dim3(BV), dim3(64), 0, stream>>>(is_input, perm, act, nAa);
    gather_CactT_kernel<<<dim3(AST, BV), dim3(256), 0, stream>>>(Ct, act, CactT);
    init_W_kernel<<<dim3(AST / 8, BV), dim3(256), 0, stream>>>(Ct, act, nAa, V, Wc);
    mix_kernel<<<dim3(BV), dim3(MTH), 0, stream>>>(CactT, Wc, act, nAa, is_input, z, V, out);
}